// Round 2
// baseline (5805.542 us; speedup 1.0000x reference)
//
#include <hip/hip_runtime.h>
#include <hip/hip_bf16.h>

#define BSZ 8
#define PAIRS 5
#define NCH 2
#define HWP 128
#define PP 64          // P*P patches per image
#define DIM 512
#define NHEAD 8
#define DHEAD 64
#define DFF 2048
#define NLAYER 6
#define SEQ 640        // PAIRS*2*PP
#define NTOK (BSZ * SEQ)   // 5120
#define FIN 10         // PAIRS*2

// ---------------- patchify: (BS,PAIRS,{init,end},C,128,128) -> A[NTOK][512] f32
__global__ __launch_bounds__(256) void k_patchify(const float* __restrict__ init,
                                                  const float* __restrict__ endp,
                                                  float* __restrict__ A) {
  int i = blockIdx.x * 256 + threadIdx.x;       // < NTOK*512
  int d = i & 511;
  int g = i >> 9;                               // token index
  int p = g & 63;
  int fi = (g >> 6) % FIN;
  int b = g / SEQ;
  int e = fi & 1;
  int pr = fi >> 1;
  int c = d >> 8;
  int r1 = (d >> 4) & 15;
  int r2 = d & 15;
  int row = ((p >> 3) << 4) + r1;
  int col = ((p & 7) << 4) + r2;
  const float* src = e ? endp : init;
  size_t off = ((size_t)((b * PAIRS + pr) * NCH + c) << 14) + (size_t)row * HWP + col;
  A[i] = src[off];
}

// ---------------- positional adds (after pre-linear)
__global__ __launch_bounds__(256) void k_addpos(float* __restrict__ f,
                                                const float* __restrict__ patch_pos,
                                                const float* __restrict__ func_pos) {
  int i = blockIdx.x * 256 + threadIdx.x;
  int d = i & 511;
  int g = i >> 9;
  int p = g & 63;
  int fi = (g >> 6) % FIN;
  f[i] += patch_pos[p * DIM + d] + func_pos[fi * DIM + d];
}

// ---------------- generic tiled GEMM: C[m,n] = act( A[m,:]·B[n,:] + bias[n] + res[m,n] )
// A f32 row-major (M,K); B f32 row-major (N,K) i.e. weight W; 64x64 tile, BK=16.
__global__ __launch_bounds__(256) void k_gemm(const float* __restrict__ A,
                                              const float* __restrict__ B,
                                              const float* __restrict__ bias,
                                              const float* __restrict__ res,
                                              float* __restrict__ C,
                                              int M, int N, int K, int act) {
  __shared__ float As[16][64];
  __shared__ float Bs[16][64];
  const int t = threadIdx.x;
  const int row0 = blockIdx.y << 6;
  const int col0 = blockIdx.x << 6;
  const int lm = t >> 2;            // 0..63 tile row for loads
  const int lk = (t & 3) << 2;      // 0,4,8,12
  const int tx = t & 15;
  const int ty = t >> 4;
  float acc[4][4] = {};
  for (int k0 = 0; k0 < K; k0 += 16) {
    float4 av = *(const float4*)(A + (size_t)(row0 + lm) * K + k0 + lk);
    As[lk + 0][lm] = av.x;
    As[lk + 1][lm] = av.y;
    As[lk + 2][lm] = av.z;
    As[lk + 3][lm] = av.w;
    float4 bv = *(const float4*)(B + (size_t)(col0 + lm) * K + k0 + lk);
    Bs[lk + 0][lm] = bv.x;
    Bs[lk + 1][lm] = bv.y;
    Bs[lk + 2][lm] = bv.z;
    Bs[lk + 3][lm] = bv.w;
    __syncthreads();
#pragma unroll
    for (int kk = 0; kk < 16; ++kk) {
      float a[4], bb[4];
#pragma unroll
      for (int i = 0; i < 4; ++i) a[i] = As[kk][ty * 4 + i];
#pragma unroll
      for (int j = 0; j < 4; ++j) bb[j] = Bs[kk][tx * 4 + j];
#pragma unroll
      for (int i = 0; i < 4; ++i)
#pragma unroll
        for (int j = 0; j < 4; ++j) acc[i][j] += a[i] * bb[j];
    }
    __syncthreads();
  }
#pragma unroll
  for (int i = 0; i < 4; ++i) {
    int m = row0 + ty * 4 + i;
#pragma unroll
    for (int j = 0; j < 4; ++j) {
      int n = col0 + tx * 4 + j;
      float v = acc[i][j];
      if (bias) v += bias[n];
      if (res) v += res[(size_t)m * N + n];
      if (act == 1) v = 0.5f * v * (1.0f + erff(v * 0.70710678118f));
      C[(size_t)m * N + n] = v;
    }
  }
}

// ---------------- attention: one block per (b, h, 16 q-rows). qkv f32 (B,S,3*D).
// block-lowtri mask: allowed k < ((q/64)+1)*64; all 16 rows share kmax (16|64).
__global__ __launch_bounds__(256) void k_attn(const float* __restrict__ qkv,
                                              float* __restrict__ o) {
  __shared__ float q_s[16][64];
  __shared__ float kv_s[64][65];    // +1 pad: phase-A lane-major reads 2-way (free)
  __shared__ float p_s[16][SEQ];
  const int t = threadIdx.x;
  const int w = t >> 6, lane = t & 63;
  const int q0 = blockIdx.x << 4;
  const int h = blockIdx.y, b = blockIdx.z;
  const float* base = qkv + (size_t)b * SEQ * (3 * DIM);
  {
    int r = t >> 4;           // 0..15
    int d0 = (t & 15) * 4;    // 0..60
    float4 v = *(const float4*)(base + (size_t)(q0 + r) * (3 * DIM) + h * DHEAD + d0);
    q_s[r][d0] = v.x; q_s[r][d0 + 1] = v.y; q_s[r][d0 + 2] = v.z; q_s[r][d0 + 3] = v.w;
  }
  const int kmax = ((q0 >> 6) + 1) << 6;
  __syncthreads();
  // phase A: scores -> p_s
  for (int kt = 0; kt < kmax; kt += 64) {
    {
      int tok = t >> 2, seg = (t & 3) * 16;
      const float* kp = base + (size_t)(kt + tok) * (3 * DIM) + DIM + h * DHEAD + seg;
#pragma unroll
      for (int i = 0; i < 4; ++i) {
        float4 v = *(const float4*)(kp + i * 4);
        kv_s[tok][seg + i * 4] = v.x; kv_s[tok][seg + i * 4 + 1] = v.y;
        kv_s[tok][seg + i * 4 + 2] = v.z; kv_s[tok][seg + i * 4 + 3] = v.w;
      }
    }
    __syncthreads();
#pragma unroll
    for (int j = 0; j < 4; ++j) {
      int r = w * 4 + j;
      float dot = 0.f;
#pragma unroll
      for (int d = 0; d < 64; ++d) dot += q_s[r][d] * kv_s[lane][d];
      p_s[r][kt + lane] = dot * 0.125f;
    }
    __syncthreads();
  }
  // phase B: softmax per row (wave w owns rows w*4..w*4+3)
  float inv[4];
#pragma unroll
  for (int j = 0; j < 4; ++j) {
    int r = w * 4 + j;
    float m = -1e30f;
    for (int kk = lane; kk < kmax; kk += 64) m = fmaxf(m, p_s[r][kk]);
#pragma unroll
    for (int off = 32; off; off >>= 1) m = fmaxf(m, __shfl_xor(m, off));
    float s = 0.f;
    for (int kk = lane; kk < kmax; kk += 64) {
      float e = __expf(p_s[r][kk] - m);
      p_s[r][kk] = e;
      s += e;
    }
#pragma unroll
    for (int off = 32; off; off >>= 1) s += __shfl_xor(s, off);
    inv[j] = 1.0f / s;
  }
  // phase C: o = P·V  (lane = output dim)
  float oa[4] = {0.f, 0.f, 0.f, 0.f};
  for (int kt = 0; kt < kmax; kt += 64) {
    __syncthreads();   // prior kv_s readers done before overwrite
    {
      int tok = t >> 2, seg = (t & 3) * 16;
      const float* vp = base + (size_t)(kt + tok) * (3 * DIM) + 2 * DIM + h * DHEAD + seg;
#pragma unroll
      for (int i = 0; i < 4; ++i) {
        float4 v = *(const float4*)(vp + i * 4);
        kv_s[tok][seg + i * 4] = v.x; kv_s[tok][seg + i * 4 + 1] = v.y;
        kv_s[tok][seg + i * 4 + 2] = v.z; kv_s[tok][seg + i * 4 + 3] = v.w;
      }
    }
    __syncthreads();
#pragma unroll
    for (int j = 0; j < 4; ++j) {
      int r = w * 4 + j;
      float a = 0.f;
#pragma unroll
      for (int kk = 0; kk < 64; ++kk) a += p_s[r][kt + kk] * kv_s[kk][lane];
      oa[j] += a;
    }
  }
#pragma unroll
  for (int j = 0; j < 4; ++j) {
    int r = w * 4 + j;
    o[((size_t)(b * SEQ + q0 + r)) * DIM + h * DHEAD + lane] = oa[j] * inv[j];
  }
}

// ---------------- LayerNorm in-place over rows of 512
__global__ __launch_bounds__(256) void k_ln(float* __restrict__ f,
                                            const float* __restrict__ s,
                                            const float* __restrict__ bia) {
  const int row = blockIdx.x;
  float* rp = f + (size_t)row * DIM;
  const int t = threadIdx.x;
  float x0 = rp[t], x1 = rp[t + 256];
  float sum = x0 + x1;
  float sq = x0 * x0 + x1 * x1;
#pragma unroll
  for (int off = 32; off; off >>= 1) {
    sum += __shfl_xor(sum, off);
    sq += __shfl_xor(sq, off);
  }
  __shared__ float rs[4], rq[4];
  const int w = t >> 6, lane = t & 63;
  if (lane == 0) { rs[w] = sum; rq[w] = sq; }
  __syncthreads();
  float tot = rs[0] + rs[1] + rs[2] + rs[3];
  float tq2 = rq[0] + rq[1] + rq[2] + rq[3];
  float mu = tot * (1.0f / 512.0f);
  float var = tq2 * (1.0f / 512.0f) - mu * mu;
  float rstd = rsqrtf(var + 1e-5f);
  rp[t] = (x0 - mu) * rstd * s[t] + bia[t];
  rp[t + 256] = (x1 - mu) * rstd * s[t + 256] + bia[t + 256];
}

// ---------------- post GEMM + depatchify: rows = init slots only (M=2560)
__global__ __launch_bounds__(256) void k_post(const float* __restrict__ f,
                                              const float* __restrict__ W,
                                              const float* __restrict__ bias,
                                              float* __restrict__ out) {
  __shared__ float As[16][64];
  __shared__ float Bs[16][64];
  const int t = threadIdx.x;
  const int row0 = blockIdx.y << 6;
  const int col0 = blockIdx.x << 6;
  const int lm = t >> 2;
  const int lk = (t & 3) << 2;
  const int tx = t & 15;
  const int ty = t >> 4;
  float acc[4][4] = {};
  const int mrow = row0 + lm;
  const int pA = mrow & 63;
  const int prA = (mrow >> 6) % PAIRS;
  const int bA = mrow / (PAIRS * PP);
  const int g = bA * SEQ + prA * 128 + pA;   // init slot token index
  for (int k0 = 0; k0 < DIM; k0 += 16) {
    float4 av = *(const float4*)(f + (size_t)g * DIM + k0 + lk);
    As[lk + 0][lm] = av.x;
    As[lk + 1][lm] = av.y;
    As[lk + 2][lm] = av.z;
    As[lk + 3][lm] = av.w;
    float4 bv = *(const float4*)(W + (size_t)(col0 + lm) * DIM + k0 + lk);
    Bs[lk + 0][lm] = bv.x;
    Bs[lk + 1][lm] = bv.y;
    Bs[lk + 2][lm] = bv.z;
    Bs[lk + 3][lm] = bv.w;
    __syncthreads();
#pragma unroll
    for (int kk = 0; kk < 16; ++kk) {
      float a[4], bb[4];
#pragma unroll
      for (int i = 0; i < 4; ++i) a[i] = As[kk][ty * 4 + i];
#pragma unroll
      for (int j = 0; j < 4; ++j) bb[j] = Bs[kk][tx * 4 + j];
#pragma unroll
      for (int i = 0; i < 4; ++i)
#pragma unroll
        for (int j = 0; j < 4; ++j) acc[i][j] += a[i] * bb[j];
    }
    __syncthreads();
  }
#pragma unroll
  for (int i = 0; i < 4; ++i) {
    int m = row0 + ty * 4 + i;
    int p = m & 63;
    int pr = (m >> 6) % PAIRS;
    int b = m / (PAIRS * PP);
#pragma unroll
    for (int j = 0; j < 4; ++j) {
      int n = col0 + tx * 4 + j;
      float v = acc[i][j] + bias[n];
      int c = n >> 8;
      int r1 = (n >> 4) & 15;
      int r2 = n & 15;
      int row = ((p >> 3) << 4) + r1;
      int col = ((p & 7) << 4) + r2;
      size_t off = ((size_t)((b * PAIRS + pr) * NCH + c) << 14) + (size_t)row * HWP + col;
      out[off] = v;
    }
  }
}

extern "C" void kernel_launch(void* const* d_in, const int* in_sizes, int n_in,
                              void* d_out, int out_size, void* d_ws, size_t ws_size,
                              hipStream_t stream) {
  const float* init = (const float*)d_in[0];
  const float* endp = (const float*)d_in[1];
  // d_in[2] c_mask: unused by reference
  const float* pre_W = (const float*)d_in[3];
  const float* pre_b = (const float*)d_in[4];
  const float* post_W = (const float*)d_in[5];
  const float* post_b = (const float*)d_in[6];
  const float* patch_pos = (const float*)d_in[7];
  const float* func_pos = (const float*)d_in[8];
  const float* Wqkv = (const float*)d_in[9];
  const float* bqkv = (const float*)d_in[10];
  const float* Wo = (const float*)d_in[11];
  const float* bo = (const float*)d_in[12];
  const float* ln1_s = (const float*)d_in[13];
  const float* ln1_b = (const float*)d_in[14];
  const float* ln2_s = (const float*)d_in[15];
  const float* ln2_b = (const float*)d_in[16];
  const float* W1 = (const float*)d_in[17];
  const float* b1 = (const float*)d_in[18];
  const float* W2 = (const float*)d_in[19];
  const float* b2 = (const float*)d_in[20];
  float* out = (float*)d_out;

  // ws layout (aliased: qkv and ffn-hidden are never simultaneously live)
  float* buf_f = (float*)d_ws;                        // NTOK*512
  float* buf_a = buf_f + (size_t)NTOK * DIM;          // NTOK*512 (patchify / attn out)
  float* buf_s = buf_a + (size_t)NTOK * DIM;          // NTOK*2048 (qkv: first NTOK*1536)

  dim3 blk(256);
  const int elems = NTOK * DIM;

  k_patchify<<<elems / 256, blk, 0, stream>>>(init, endp, buf_a);
  k_gemm<<<dim3(DIM / 64, NTOK / 64), blk, 0, stream>>>(buf_a, pre_W, pre_b, nullptr,
                                                        buf_f, NTOK, DIM, DIM, 0);
  k_addpos<<<elems / 256, blk, 0, stream>>>(buf_f, patch_pos, func_pos);

  for (int l = 0; l < NLAYER; ++l) {
    k_gemm<<<dim3(3 * DIM / 64, NTOK / 64), blk, 0, stream>>>(
        buf_f, Wqkv + (size_t)l * 3 * DIM * DIM, bqkv + (size_t)l * 3 * DIM, nullptr,
        buf_s, NTOK, 3 * DIM, DIM, 0);
    k_attn<<<dim3(SEQ / 16, NHEAD, BSZ), blk, 0, stream>>>(buf_s, buf_a);
    k_gemm<<<dim3(DIM / 64, NTOK / 64), blk, 0, stream>>>(
        buf_a, Wo + (size_t)l * DIM * DIM, bo + (size_t)l * DIM, buf_f,
        buf_f, NTOK, DIM, DIM, 0);
    k_ln<<<NTOK, blk, 0, stream>>>(buf_f, ln1_s + (size_t)l * DIM, ln1_b + (size_t)l * DIM);
    k_gemm<<<dim3(DFF / 64, NTOK / 64), blk, 0, stream>>>(
        buf_f, W1 + (size_t)l * DFF * DIM, b1 + (size_t)l * DFF, nullptr,
        buf_s, NTOK, DFF, DIM, 1);
    k_gemm<<<dim3(DIM / 64, NTOK / 64), blk, 0, stream>>>(
        buf_s, W2 + (size_t)l * DIM * DFF, b2 + (size_t)l * DIM, buf_f,
        buf_f, NTOK, DIM, DFF, 0);
    k_ln<<<NTOK, blk, 0, stream>>>(buf_f, ln2_s + (size_t)l * DIM, ln2_b + (size_t)l * DIM);
  }

  k_post<<<dim3(DIM / 64, (BSZ * PAIRS * PP) / 64), blk, 0, stream>>>(buf_f, post_W,
                                                                      post_b, out);
}

// Round 3
// 1453.910 us; speedup vs baseline: 3.9931x; 3.9931x over previous
//
#include <hip/hip_runtime.h>
#include <hip/hip_bf16.h>

#define BSZ 8
#define PAIRS 5
#define NCH 2
#define HWP 128
#define PP 64
#define DIM 512
#define NHEAD 8
#define DHEAD 64
#define DFF 2048
#define NLAYER 6
#define SEQ 640
#define NTOK (BSZ * SEQ)   // 5120
#define FIN 10

typedef unsigned short u16;
typedef __bf16 bf16_t;
typedef __attribute__((ext_vector_type(8))) __bf16 bf16x8;
typedef __attribute__((ext_vector_type(4))) float f32x4;
#define MFMA16(a, b, c) __builtin_amdgcn_mfma_f32_16x16x32_bf16(a, b, c, 0, 0, 0)

__device__ __forceinline__ u16 f2b(float x) {   // RNE f32->bf16
  unsigned u = __float_as_uint(x);
  return (u16)((u + 0x7fffu + ((u >> 16) & 1u)) >> 16);
}

// ---------------- f32 -> bf16 convert
__global__ __launch_bounds__(256) void k_cvt(const float* __restrict__ src,
                                             u16* __restrict__ dst, int n) {
  int i = blockIdx.x * 256 + threadIdx.x;
  if (i < n) dst[i] = f2b(src[i]);
}

// ---------------- patchify -> bf16 A[NTOK][512]
__global__ __launch_bounds__(256) void k_patchify(const float* __restrict__ init,
                                                  const float* __restrict__ endp,
                                                  u16* __restrict__ A) {
  int i = blockIdx.x * 256 + threadIdx.x;
  int d = i & 511;
  int g = i >> 9;
  int p = g & 63;
  int fi = (g >> 6) % FIN;
  int b = g / SEQ;
  int e = fi & 1;
  int pr = fi >> 1;
  int c = d >> 8;
  int r1 = (d >> 4) & 15;
  int r2 = d & 15;
  int row = ((p >> 3) << 4) + r1;
  int col = ((p & 7) << 4) + r2;
  const float* src = e ? endp : init;
  size_t off = ((size_t)((b * PAIRS + pr) * NCH + c) << 14) + (size_t)row * HWP + col;
  A[i] = f2b(src[off]);
}

// ---------------- positional adds: f32 master += pos; also emit bf16 copy
__global__ __launch_bounds__(256) void k_addpos(float* __restrict__ f,
                                                u16* __restrict__ fb,
                                                const float* __restrict__ patch_pos,
                                                const float* __restrict__ func_pos) {
  int i = blockIdx.x * 256 + threadIdx.x;
  int d = i & 511;
  int g = i >> 9;
  int p = g & 63;
  int fi = (g >> 6) % FIN;
  float v = f[i] + patch_pos[p * DIM + d] + func_pos[fi * DIM + d];
  f[i] = v;
  fb[i] = f2b(v);
}

// ---------------- bf16 MFMA GEMM: C[m,n] = act(A[m,:]·W[n,:] + bias[n] + res)
// A bf16 [M][K], B bf16 [N][K]; 128x128 tile, BK=32, 4 waves in 2x2.
__global__ __launch_bounds__(256) void k_mm(const u16* __restrict__ A,
                                            const u16* __restrict__ B,
                                            const float* __restrict__ bias,
                                            const float* __restrict__ res,
                                            float* __restrict__ outF,
                                            u16* __restrict__ outB,
                                            int M, int N, int K, int act) {
  __shared__ bf16_t As[128][40];
  __shared__ bf16_t Bs[128][40];
  const int t = threadIdx.x;
  const int w = t >> 6, lane = t & 63, quad = lane >> 4, l16 = lane & 15;
  const int row0 = blockIdx.y << 7, col0 = blockIdx.x << 7;
  const int mB = (w & 1) << 6, nB = (w >> 1) << 6;
  const int lr = t >> 2;           // 0..63
  const int ls = (t & 3) << 3;     // 0,8,16,24
  f32x4 acc[4][4];
#pragma unroll
  for (int i = 0; i < 4; ++i)
#pragma unroll
    for (int j = 0; j < 4; ++j) acc[i][j] = (f32x4){0.f, 0.f, 0.f, 0.f};

  for (int k0 = 0; k0 < K; k0 += 32) {
#pragma unroll
    for (int ph = 0; ph < 2; ++ph) {
      int r = lr + (ph << 6);
      *(bf16x8*)&As[r][ls] = *(const bf16x8*)(const void*)(A + (size_t)(row0 + r) * K + k0 + ls);
      *(bf16x8*)&Bs[r][ls] = *(const bf16x8*)(const void*)(B + (size_t)(col0 + r) * K + k0 + ls);
    }
    __syncthreads();
    bf16x8 af[4], bfr[4];
#pragma unroll
    for (int i = 0; i < 4; ++i) af[i] = *(const bf16x8*)&As[mB + i * 16 + l16][quad * 8];
#pragma unroll
    for (int j = 0; j < 4; ++j) bfr[j] = *(const bf16x8*)&Bs[nB + j * 16 + l16][quad * 8];
#pragma unroll
    for (int i = 0; i < 4; ++i)
#pragma unroll
      for (int j = 0; j < 4; ++j) acc[i][j] = MFMA16(af[i], bfr[j], acc[i][j]);
    __syncthreads();
  }
#pragma unroll
  for (int i = 0; i < 4; ++i) {
#pragma unroll
    for (int reg = 0; reg < 4; ++reg) {
      int m = row0 + mB + i * 16 + quad * 4 + reg;
#pragma unroll
      for (int j = 0; j < 4; ++j) {
        int n = col0 + nB + j * 16 + l16;
        float v = acc[i][j][reg] + bias[n];
        if (res) v += res[(size_t)m * N + n];
        if (act) v = 0.5f * v * (1.0f + erff(v * 0.70710678118f));
        if (outF) outF[(size_t)m * N + n] = v;
        if (outB) outB[(size_t)m * N + n] = f2b(v);
      }
    }
  }
}

// ---------------- fused flash attention (bf16 MFMA). qkv bf16 [B][S][3*DIM].
// Block = (qblk, h, b): 64 q-rows, k-tiles 0..qblk (mask is 64-aligned).
__global__ __launch_bounds__(256) void k_attn(const u16* __restrict__ qkv,
                                              u16* __restrict__ o) {
  __shared__ bf16_t Qs[64][72];
  __shared__ bf16_t Ks[64][72];
  __shared__ bf16_t Vs[64][72];   // transposed: Vs[d][tok]
  __shared__ bf16_t Ps[64][72];
  const int t = threadIdx.x;
  const int w = t >> 6, lane = t & 63, quad = lane >> 4, l16 = lane & 15;
  const int qblk = blockIdx.x, h = blockIdx.y, b = blockIdx.z;
  const int q0 = qblk << 6;
  const u16* base = qkv + (size_t)b * SEQ * (3 * DIM);
  const int sr = t >> 2;            // 0..63 staging row
  const int sd = (t & 3) << 4;      // 0,16,32,48
  {
    const u16* qp = base + (size_t)(q0 + sr) * (3 * DIM) + h * DHEAD + sd;
    *(bf16x8*)&Qs[sr][sd] = *(const bf16x8*)(const void*)qp;
    *(bf16x8*)&Qs[sr][sd + 8] = *(const bf16x8*)(const void*)(qp + 8);
  }
  __syncthreads();
  bf16x8 aQ0 = *(const bf16x8*)&Qs[w * 16 + l16][quad * 8];
  bf16x8 aQ1 = *(const bf16x8*)&Qs[w * 16 + l16][32 + quad * 8];
  f32x4 accO[4];
#pragma unroll
  for (int j = 0; j < 4; ++j) accO[j] = (f32x4){0.f, 0.f, 0.f, 0.f};
  float mSt[4] = {-1e30f, -1e30f, -1e30f, -1e30f};
  float lSt[4] = {0.f, 0.f, 0.f, 0.f};
  const int ntile = qblk + 1;
  for (int kt = 0; kt < ntile; ++kt) {
    {
      const u16* kp = base + (size_t)(kt * 64 + sr) * (3 * DIM) + DIM + h * DHEAD + sd;
      *(bf16x8*)&Ks[sr][sd] = *(const bf16x8*)(const void*)kp;
      *(bf16x8*)&Ks[sr][sd + 8] = *(const bf16x8*)(const void*)(kp + 8);
      const u16* vp = base + (size_t)(kt * 64 + sr) * (3 * DIM) + 2 * DIM + h * DHEAD + sd;
      bf16x8 v0 = *(const bf16x8*)(const void*)vp;
      bf16x8 v1 = *(const bf16x8*)(const void*)(vp + 8);
#pragma unroll
      for (int e = 0; e < 8; ++e) Vs[sd + e][sr] = v0[e];
#pragma unroll
      for (int e = 0; e < 8; ++e) Vs[sd + 8 + e][sr] = v1[e];
    }
    __syncthreads();
    // S = scale * Q·K^T  (rows: quad*4+reg; cols: j*16+l16 = token)
    f32x4 s[4];
#pragma unroll
    for (int j = 0; j < 4; ++j) {
      bf16x8 b0 = *(const bf16x8*)&Ks[j * 16 + l16][quad * 8];
      bf16x8 b1 = *(const bf16x8*)&Ks[j * 16 + l16][32 + quad * 8];
      s[j] = (f32x4){0.f, 0.f, 0.f, 0.f};
      s[j] = MFMA16(aQ0, b0, s[j]);
      s[j] = MFMA16(aQ1, b1, s[j]);
      s[j] *= 0.125f;
    }
    // online softmax per row
#pragma unroll
    for (int reg = 0; reg < 4; ++reg) {
      float mx = fmaxf(fmaxf(s[0][reg], s[1][reg]), fmaxf(s[2][reg], s[3][reg]));
      mx = fmaxf(mx, __shfl_xor(mx, 1));
      mx = fmaxf(mx, __shfl_xor(mx, 2));
      mx = fmaxf(mx, __shfl_xor(mx, 4));
      mx = fmaxf(mx, __shfl_xor(mx, 8));
      float mNew = fmaxf(mSt[reg], mx);
      float alpha = __expf(mSt[reg] - mNew);
      mSt[reg] = mNew;
      float rs = 0.f;
#pragma unroll
      for (int j = 0; j < 4; ++j) {
        float p = __expf(s[j][reg] - mNew);
        s[j][reg] = p;
        rs += p;
      }
      rs += __shfl_xor(rs, 1);
      rs += __shfl_xor(rs, 2);
      rs += __shfl_xor(rs, 4);
      rs += __shfl_xor(rs, 8);
      lSt[reg] = lSt[reg] * alpha + rs;
#pragma unroll
      for (int j = 0; j < 4; ++j) accO[j][reg] *= alpha;
    }
    // P (C-layout) -> Ps[m][tok] (A-layout source)
#pragma unroll
    for (int j = 0; j < 4; ++j)
#pragma unroll
      for (int reg = 0; reg < 4; ++reg)
        *(u16*)&Ps[w * 16 + quad * 4 + reg][j * 16 + l16] = f2b(s[j][reg]);
    __syncthreads();
    bf16x8 aP0 = *(const bf16x8*)&Ps[w * 16 + l16][quad * 8];
    bf16x8 aP1 = *(const bf16x8*)&Ps[w * 16 + l16][32 + quad * 8];
#pragma unroll
    for (int jd = 0; jd < 4; ++jd) {
      bf16x8 b0 = *(const bf16x8*)&Vs[jd * 16 + l16][quad * 8];
      bf16x8 b1 = *(const bf16x8*)&Vs[jd * 16 + l16][32 + quad * 8];
      accO[jd] = MFMA16(aP0, b0, accO[jd]);
      accO[jd] = MFMA16(aP1, b1, accO[jd]);
    }
    __syncthreads();
  }
#pragma unroll
  for (int reg = 0; reg < 4; ++reg) {
    float inv = 1.0f / lSt[reg];
    int row = q0 + w * 16 + quad * 4 + reg;
#pragma unroll
    for (int jd = 0; jd < 4; ++jd)
      o[((size_t)(b * SEQ + row)) * DIM + h * DHEAD + jd * 16 + l16] =
          f2b(accO[jd][reg] * inv);
  }
}

// ---------------- LayerNorm: f32 master in/out + bf16 copy out
__global__ __launch_bounds__(256) void k_ln(float* __restrict__ f,
                                            u16* __restrict__ fb,
                                            const float* __restrict__ s,
                                            const float* __restrict__ bia) {
  const int row = blockIdx.x;
  float* rp = f + (size_t)row * DIM;
  const int t = threadIdx.x;
  float x0 = rp[t], x1 = rp[t + 256];
  float sum = x0 + x1;
  float sq = x0 * x0 + x1 * x1;
#pragma unroll
  for (int off = 32; off; off >>= 1) {
    sum += __shfl_xor(sum, off);
    sq += __shfl_xor(sq, off);
  }
  __shared__ float rs[4], rq[4];
  const int w = t >> 6, lane = t & 63;
  if (lane == 0) { rs[w] = sum; rq[w] = sq; }
  __syncthreads();
  float tot = rs[0] + rs[1] + rs[2] + rs[3];
  float tq2 = rq[0] + rq[1] + rq[2] + rq[3];
  float mu = tot * (1.0f / 512.0f);
  float var = tq2 * (1.0f / 512.0f) - mu * mu;
  float rstd = rsqrtf(var + 1e-5f);
  float v0 = (x0 - mu) * rstd * s[t] + bia[t];
  float v1 = (x1 - mu) * rstd * s[t + 256] + bia[t + 256];
  rp[t] = v0;
  rp[t + 256] = v1;
  fb[(size_t)row * DIM + t] = f2b(v0);
  fb[(size_t)row * DIM + t + 256] = f2b(v1);
}

// ---------------- post GEMM (MFMA) + depatchify scatter. M=2560, N=K=512.
__global__ __launch_bounds__(256) void k_post(const u16* __restrict__ A,   // buf_fb
                                              const u16* __restrict__ B,   // post_W bf16
                                              const float* __restrict__ bias,
                                              float* __restrict__ out) {
  __shared__ bf16_t As[128][40];
  __shared__ bf16_t Bs[128][40];
  const int t = threadIdx.x;
  const int w = t >> 6, lane = t & 63, quad = lane >> 4, l16 = lane & 15;
  const int row0 = blockIdx.y << 7, col0 = blockIdx.x << 7;
  const int mB = (w & 1) << 6, nB = (w >> 1) << 6;
  const int lr = t >> 2;
  const int ls = (t & 3) << 3;
  f32x4 acc[4][4];
#pragma unroll
  for (int i = 0; i < 4; ++i)
#pragma unroll
    for (int j = 0; j < 4; ++j) acc[i][j] = (f32x4){0.f, 0.f, 0.f, 0.f};
  for (int k0 = 0; k0 < DIM; k0 += 32) {
#pragma unroll
    for (int ph = 0; ph < 2; ++ph) {
      int r = lr + (ph << 6);
      int mrow = row0 + r;
      int pA = mrow & 63;
      int prA = (mrow >> 6) % PAIRS;
      int bA = mrow / (PAIRS * PP);
      int g = bA * SEQ + prA * 128 + pA;     // init-slot token
      *(bf16x8*)&As[r][ls] = *(const bf16x8*)(const void*)(A + (size_t)g * DIM + k0 + ls);
      *(bf16x8*)&Bs[r][ls] = *(const bf16x8*)(const void*)(B + (size_t)(col0 + r) * DIM + k0 + ls);
    }
    __syncthreads();
    bf16x8 af[4], bfr[4];
#pragma unroll
    for (int i = 0; i < 4; ++i) af[i] = *(const bf16x8*)&As[mB + i * 16 + l16][quad * 8];
#pragma unroll
    for (int j = 0; j < 4; ++j) bfr[j] = *(const bf16x8*)&Bs[nB + j * 16 + l16][quad * 8];
#pragma unroll
    for (int i = 0; i < 4; ++i)
#pragma unroll
      for (int j = 0; j < 4; ++j) acc[i][j] = MFMA16(af[i], bfr[j], acc[i][j]);
    __syncthreads();
  }
#pragma unroll
  for (int i = 0; i < 4; ++i) {
#pragma unroll
    for (int reg = 0; reg < 4; ++reg) {
      int m = row0 + mB + i * 16 + quad * 4 + reg;
      int p = m & 63;
      int pr = (m >> 6) % PAIRS;
      int b = m / (PAIRS * PP);
#pragma unroll
      for (int j = 0; j < 4; ++j) {
        int n = col0 + nB + j * 16 + l16;
        float v = acc[i][j][reg] + bias[n];
        int c = n >> 8;
        int r1 = (n >> 4) & 15;
        int r2 = n & 15;
        int row = ((p >> 3) << 4) + r1;
        int col = ((p & 7) << 4) + r2;
        size_t off = ((size_t)((b * PAIRS + pr) * NCH + c) << 14) + (size_t)row * HWP + col;
        out[off] = v;
      }
    }
  }
}

extern "C" void kernel_launch(void* const* d_in, const int* in_sizes, int n_in,
                              void* d_out, int out_size, void* d_ws, size_t ws_size,
                              hipStream_t stream) {
  const float* init = (const float*)d_in[0];
  const float* endp = (const float*)d_in[1];
  const float* pre_W = (const float*)d_in[3];
  const float* pre_b = (const float*)d_in[4];
  const float* post_W = (const float*)d_in[5];
  const float* post_b = (const float*)d_in[6];
  const float* patch_pos = (const float*)d_in[7];
  const float* func_pos = (const float*)d_in[8];
  const float* Wqkv = (const float*)d_in[9];
  const float* bqkv = (const float*)d_in[10];
  const float* Wo = (const float*)d_in[11];
  const float* bo = (const float*)d_in[12];
  const float* ln1_s = (const float*)d_in[13];
  const float* ln1_b = (const float*)d_in[14];
  const float* ln2_s = (const float*)d_in[15];
  const float* ln2_b = (const float*)d_in[16];
  const float* W1 = (const float*)d_in[17];
  const float* b1 = (const float*)d_in[18];
  const float* W2 = (const float*)d_in[19];
  const float* b2 = (const float*)d_in[20];
  float* out = (float*)d_out;

  // ws layout (bytes), total ~49.3 MB
  char* p = (char*)d_ws;
  float* buf_f = (float*)p;                 p += (size_t)NTOK * DIM * 4;       // f32 master
  u16* buf_fb = (u16*)p;                    p += (size_t)NTOK * DIM * 2;       // bf16 stream
  u16* buf_attn = (u16*)p;                  p += (size_t)NTOK * DIM * 2;       // attn out bf16
  u16* shared_b = (u16*)p;                  p += (size_t)NTOK * DFF * 2;       // qkv/hid/patch alias
  u16* wB = (u16*)p;                        p += (size_t)3145728 * 2;          // per-layer weights
  u16* wPre = (u16*)p;                      p += (size_t)DIM * DIM * 2;
  u16* wPost = (u16*)p;                     p += (size_t)DIM * DIM * 2;
  u16* buf_qkv = shared_b;
  u16* buf_hid = shared_b;
  u16* buf_patch = shared_b;

  dim3 blk(256);
  const int elems = NTOK * DIM;
  const int W_QKV = 3 * DIM * DIM;      // 786432
  const int W_O = DIM * DIM;            // 262144
  const int W_1 = DFF * DIM;            // 1048576
  const int OFF_O = W_QKV;
  const int OFF_1 = W_QKV + W_O;
  const int OFF_2 = W_QKV + W_O + W_1;

  k_cvt<<<(DIM * DIM + 255) / 256, blk, 0, stream>>>(pre_W, wPre, DIM * DIM);
  k_cvt<<<(DIM * DIM + 255) / 256, blk, 0, stream>>>(post_W, wPost, DIM * DIM);
  k_patchify<<<elems / 256, blk, 0, stream>>>(init, endp, buf_patch);
  k_mm<<<dim3(DIM / 128, NTOK / 128), blk, 0, stream>>>(
      buf_patch, wPre, pre_b, nullptr, buf_f, nullptr, NTOK, DIM, DIM, 0);
  k_addpos<<<elems / 256, blk, 0, stream>>>(buf_f, buf_fb, patch_pos, func_pos);

  for (int l = 0; l < NLAYER; ++l) {
    k_cvt<<<(W_QKV + 255) / 256, blk, 0, stream>>>(Wqkv + (size_t)l * W_QKV, wB, W_QKV);
    k_cvt<<<(W_O + 255) / 256, blk, 0, stream>>>(Wo + (size_t)l * W_O, wB + OFF_O, W_O);
    k_cvt<<<(W_1 + 255) / 256, blk, 0, stream>>>(W1 + (size_t)l * W_1, wB + OFF_1, W_1);
    k_cvt<<<(W_1 + 255) / 256, blk, 0, stream>>>(W2 + (size_t)l * W_1, wB + OFF_2, W_1);

    k_mm<<<dim3(3 * DIM / 128, NTOK / 128), blk, 0, stream>>>(
        buf_fb, wB, bqkv + (size_t)l * 3 * DIM, nullptr, nullptr, buf_qkv,
        NTOK, 3 * DIM, DIM, 0);
    k_attn<<<dim3(SEQ / 64, NHEAD, BSZ), blk, 0, stream>>>(buf_qkv, buf_attn);
    k_mm<<<dim3(DIM / 128, NTOK / 128), blk, 0, stream>>>(
        buf_attn, wB + OFF_O, bo + (size_t)l * DIM, buf_f, buf_f, nullptr,
        NTOK, DIM, DIM, 0);
    k_ln<<<NTOK, blk, 0, stream>>>(buf_f, buf_fb, ln1_s + (size_t)l * DIM,
                                   ln1_b + (size_t)l * DIM);
    k_mm<<<dim3(DFF / 128, NTOK / 128), blk, 0, stream>>>(
        buf_fb, wB + OFF_1, b1 + (size_t)l * DFF, nullptr, nullptr, buf_hid,
        NTOK, DFF, DIM, 1);
    k_mm<<<dim3(DIM / 128, NTOK / 128), blk, 0, stream>>>(
        buf_hid, wB + OFF_2, b2 + (size_t)l * DIM, buf_f, buf_f, nullptr,
        NTOK, DIM, DFF, 0);
    k_ln<<<NTOK, blk, 0, stream>>>(buf_f, buf_fb, ln2_s + (size_t)l * DIM,
                                   ln2_b + (size_t)l * DIM);
  }

  k_post<<<dim3(DIM / 128, (BSZ * PAIRS * PP) / 128), blk, 0, stream>>>(
      buf_fb, wPost, post_b, out);
}

// Round 4
// 1162.569 us; speedup vs baseline: 4.9937x; 1.2506x over previous
//
#include <hip/hip_runtime.h>
#include <hip/hip_bf16.h>

#define BSZ 8
#define PAIRS 5
#define NCH 2
#define HWP 128
#define PP 64
#define DIM 512
#define NHEAD 8
#define DHEAD 64
#define DFF 2048
#define NLAYER 6
#define SEQ 640
#define NTOK (BSZ * SEQ)   // 5120
#define FIN 10
#define MPOST (BSZ * PAIRS * PP)   // 2560

typedef unsigned short u16;
typedef __bf16 bf16_t;
typedef __attribute__((ext_vector_type(8))) __bf16 bf16x8;
typedef __attribute__((ext_vector_type(4))) float f32x4;
#define MFMA16(a, b, c) __builtin_amdgcn_mfma_f32_16x16x32_bf16(a, b, c, 0, 0, 0)

__device__ __forceinline__ u16 f2b(float x) {   // RNE f32->bf16
  unsigned u = __float_as_uint(x);
  return (u16)((u + 0x7fffu + ((u >> 16) & 1u)) >> 16);
}

// ---------------- pre/post weight convert (one launch)
__global__ __launch_bounds__(256) void k_cvt2(const float* __restrict__ a,
                                              const float* __restrict__ b,
                                              u16* __restrict__ da,
                                              u16* __restrict__ db, int n) {
  int i = blockIdx.x * 256 + threadIdx.x;
  if (i < n) { da[i] = f2b(a[i]); db[i] = f2b(b[i]); }
}

// ---------------- per-layer weight convert: 4 regions in one launch
#define W_QKV (3 * DIM * DIM)   // 786432
#define W_O (DIM * DIM)         // 262144
#define W_1 (DFF * DIM)         // 1048576
#define OFF_O W_QKV
#define OFF_1 (W_QKV + W_O)
#define OFF_2 (W_QKV + W_O + W_1)
#define W_ALL (W_QKV + W_O + 2 * W_1)   // 3145728
__global__ __launch_bounds__(256) void k_cvtw(const float* __restrict__ wq,
                                              const float* __restrict__ wo,
                                              const float* __restrict__ w1,
                                              const float* __restrict__ w2,
                                              u16* __restrict__ dst) {
  int i = blockIdx.x * 256 + threadIdx.x;   // < W_ALL
  const float* src;
  int off;
  if (i < OFF_O) { src = wq; off = i; }
  else if (i < OFF_1) { src = wo; off = i - OFF_O; }
  else if (i < OFF_2) { src = w1; off = i - OFF_1; }
  else { src = w2; off = i - OFF_2; }
  dst[i] = f2b(src[off]);
}

// ---------------- patchify -> bf16 A[NTOK][512]
__global__ __launch_bounds__(256) void k_patchify(const float* __restrict__ init,
                                                  const float* __restrict__ endp,
                                                  u16* __restrict__ A) {
  int i = blockIdx.x * 256 + threadIdx.x;
  int d = i & 511;
  int g = i >> 9;
  int p = g & 63;
  int fi = (g >> 6) % FIN;
  int b = g / SEQ;
  int e = fi & 1;
  int pr = fi >> 1;
  int c = d >> 8;
  int r1 = (d >> 4) & 15;
  int r2 = d & 15;
  int row = ((p >> 3) << 4) + r1;
  int col = ((p & 7) << 4) + r2;
  const float* src = e ? endp : init;
  size_t off = ((size_t)((b * PAIRS + pr) * NCH + c) << 14) + (size_t)row * HWP + col;
  A[i] = f2b(src[off]);
}

// ---------------- pre-bias + positional adds from raw GEMM partial
__global__ __launch_bounds__(256) void k_addpos(const float* __restrict__ pin,
                                                float* __restrict__ f,
                                                u16* __restrict__ fb,
                                                const float* __restrict__ pre_b,
                                                const float* __restrict__ patch_pos,
                                                const float* __restrict__ func_pos) {
  int i = blockIdx.x * 256 + threadIdx.x;
  int d = i & 511;
  int g = i >> 9;
  int p = g & 63;
  int fi = (g >> 6) % FIN;
  float v = pin[i] + pre_b[d] + patch_pos[p * DIM + d] + func_pos[fi * DIM + d];
  f[i] = v;
  fb[i] = f2b(v);
}

// ---------------- bf16 MFMA GEMM, software-pipelined double-buffer K-loop.
// A bf16 [M][K], B bf16 [N][K]; 128x128 tile, BK=32, 4 waves 2x2.
// outB != null: C = act(A·B^T + bias) -> bf16.  else: raw f32 partial (split-K z).
__global__ __launch_bounds__(256) void k_mm(const u16* __restrict__ A,
                                            const u16* __restrict__ B,
                                            const float* __restrict__ bias,
                                            u16* __restrict__ outB,
                                            float* __restrict__ outP,
                                            int M, int N, int K, int Kblk, int act) {
  __shared__ bf16_t As[2][128][40];
  __shared__ bf16_t Bs[2][128][40];
  const int t = threadIdx.x;
  const int w = t >> 6, lane = t & 63, quad = lane >> 4, l16 = lane & 15;
  const int row0 = blockIdx.y << 7, col0 = blockIdx.x << 7;
  const size_t kOff = (size_t)blockIdx.z * Kblk;
  const int mB = (w & 1) << 6, nB = (w >> 1) << 6;
  const int lr = t >> 2;           // 0..63
  const int ls = (t & 3) << 3;     // 0,8,16,24
  const u16* Ap = A + (size_t)(row0 + lr) * K + kOff + ls;
  const u16* Bp = B + (size_t)(col0 + lr) * K + kOff + ls;
  const size_t rstep = (size_t)64 * K;
  f32x4 acc[4][4];
#pragma unroll
  for (int i = 0; i < 4; ++i)
#pragma unroll
    for (int j = 0; j < 4; ++j) acc[i][j] = (f32x4){0.f, 0.f, 0.f, 0.f};
  const int iters = Kblk >> 5;
  {
    bf16x8 a0 = *(const bf16x8*)(const void*)Ap;
    bf16x8 a1 = *(const bf16x8*)(const void*)(Ap + rstep);
    bf16x8 b0 = *(const bf16x8*)(const void*)Bp;
    bf16x8 b1 = *(const bf16x8*)(const void*)(Bp + rstep);
    *(bf16x8*)&As[0][lr][ls] = a0;
    *(bf16x8*)&As[0][lr + 64][ls] = a1;
    *(bf16x8*)&Bs[0][lr][ls] = b0;
    *(bf16x8*)&Bs[0][lr + 64][ls] = b1;
  }
  __syncthreads();
  for (int it = 0;;) {
    const int cur = it & 1;
    const bool more = (it + 1 < iters);
    bf16x8 na0, na1, nb0, nb1;
    if (more) {                       // prefetch next tile (in flight during MFMAs)
      const int kn = (it + 1) << 5;
      na0 = *(const bf16x8*)(const void*)(Ap + kn);
      na1 = *(const bf16x8*)(const void*)(Ap + rstep + kn);
      nb0 = *(const bf16x8*)(const void*)(Bp + kn);
      nb1 = *(const bf16x8*)(const void*)(Bp + rstep + kn);
    }
    bf16x8 af[4], bfr[4];
#pragma unroll
    for (int i = 0; i < 4; ++i) af[i] = *(const bf16x8*)&As[cur][mB + i * 16 + l16][quad * 8];
#pragma unroll
    for (int j = 0; j < 4; ++j) bfr[j] = *(const bf16x8*)&Bs[cur][nB + j * 16 + l16][quad * 8];
#pragma unroll
    for (int i = 0; i < 4; ++i)
#pragma unroll
      for (int j = 0; j < 4; ++j) acc[i][j] = MFMA16(af[i], bfr[j], acc[i][j]);
    if (!more) break;
    const int nxt = cur ^ 1;
    *(bf16x8*)&As[nxt][lr][ls] = na0;
    *(bf16x8*)&As[nxt][lr + 64][ls] = na1;
    *(bf16x8*)&Bs[nxt][lr][ls] = nb0;
    *(bf16x8*)&Bs[nxt][lr + 64][ls] = nb1;
    __syncthreads();
    ++it;
  }
  if (outB) {
#pragma unroll
    for (int i = 0; i < 4; ++i)
#pragma unroll
      for (int reg = 0; reg < 4; ++reg) {
        int m = row0 + mB + i * 16 + quad * 4 + reg;
#pragma unroll
        for (int j = 0; j < 4; ++j) {
          int n = col0 + nB + j * 16 + l16;
          float v = acc[i][j][reg] + bias[n];
          if (act) v = 0.5f * v * (1.0f + erff(v * 0.70710678118f));
          outB[(size_t)m * N + n] = f2b(v);
        }
      }
  } else {
    float* dst = outP + (size_t)blockIdx.z * M * N;
#pragma unroll
    for (int i = 0; i < 4; ++i)
#pragma unroll
      for (int reg = 0; reg < 4; ++reg) {
        int m = row0 + mB + i * 16 + quad * 4 + reg;
#pragma unroll
        for (int j = 0; j < 4; ++j) {
          int n = col0 + nB + j * 16 + l16;
          dst[(size_t)m * N + n] = acc[i][j][reg];
        }
      }
  }
}

// ---------------- fused flash attention (bf16 MFMA). qkv bf16 [B][S][3*DIM].
__global__ __launch_bounds__(256) void k_attn(const u16* __restrict__ qkv,
                                              u16* __restrict__ o) {
  __shared__ bf16_t Qs[64][72];
  __shared__ bf16_t Ks[64][72];
  __shared__ bf16_t Vs[64][72];   // transposed: Vs[d][tok]
  __shared__ bf16_t Ps[64][72];
  const int t = threadIdx.x;
  const int w = t >> 6, lane = t & 63, quad = lane >> 4, l16 = lane & 15;
  const int qblk = blockIdx.x, h = blockIdx.y, b = blockIdx.z;
  const int q0 = qblk << 6;
  const u16* base = qkv + (size_t)b * SEQ * (3 * DIM);
  const int sr = t >> 2;
  const int sd = (t & 3) << 4;
  {
    const u16* qp = base + (size_t)(q0 + sr) * (3 * DIM) + h * DHEAD + sd;
    *(bf16x8*)&Qs[sr][sd] = *(const bf16x8*)(const void*)qp;
    *(bf16x8*)&Qs[sr][sd + 8] = *(const bf16x8*)(const void*)(qp + 8);
  }
  __syncthreads();
  bf16x8 aQ0 = *(const bf16x8*)&Qs[w * 16 + l16][quad * 8];
  bf16x8 aQ1 = *(const bf16x8*)&Qs[w * 16 + l16][32 + quad * 8];
  f32x4 accO[4];
#pragma unroll
  for (int j = 0; j < 4; ++j) accO[j] = (f32x4){0.f, 0.f, 0.f, 0.f};
  float mSt[4] = {-1e30f, -1e30f, -1e30f, -1e30f};
  float lSt[4] = {0.f, 0.f, 0.f, 0.f};
  const int ntile = qblk + 1;
  for (int kt = 0; kt < ntile; ++kt) {
    {
      const u16* kp = base + (size_t)(kt * 64 + sr) * (3 * DIM) + DIM + h * DHEAD + sd;
      *(bf16x8*)&Ks[sr][sd] = *(const bf16x8*)(const void*)kp;
      *(bf16x8*)&Ks[sr][sd + 8] = *(const bf16x8*)(const void*)(kp + 8);
      const u16* vp = base + (size_t)(kt * 64 + sr) * (3 * DIM) + 2 * DIM + h * DHEAD + sd;
      bf16x8 v0 = *(const bf16x8*)(const void*)vp;
      bf16x8 v1 = *(const bf16x8*)(const void*)(vp + 8);
#pragma unroll
      for (int e = 0; e < 8; ++e) Vs[sd + e][sr] = v0[e];
#pragma unroll
      for (int e = 0; e < 8; ++e) Vs[sd + 8 + e][sr] = v1[e];
    }
    __syncthreads();
    f32x4 s[4];
#pragma unroll
    for (int j = 0; j < 4; ++j) {
      bf16x8 b0 = *(const bf16x8*)&Ks[j * 16 + l16][quad * 8];
      bf16x8 b1 = *(const bf16x8*)&Ks[j * 16 + l16][32 + quad * 8];
      s[j] = (f32x4){0.f, 0.f, 0.f, 0.f};
      s[j] = MFMA16(aQ0, b0, s[j]);
      s[j] = MFMA16(aQ1, b1, s[j]);
      s[j] *= 0.125f;
    }
#pragma unroll
    for (int reg = 0; reg < 4; ++reg) {
      float mx = fmaxf(fmaxf(s[0][reg], s[1][reg]), fmaxf(s[2][reg], s[3][reg]));
      mx = fmaxf(mx, __shfl_xor(mx, 1));
      mx = fmaxf(mx, __shfl_xor(mx, 2));
      mx = fmaxf(mx, __shfl_xor(mx, 4));
      mx = fmaxf(mx, __shfl_xor(mx, 8));
      float mNew = fmaxf(mSt[reg], mx);
      float alpha = __expf(mSt[reg] - mNew);
      mSt[reg] = mNew;
      float rs = 0.f;
#pragma unroll
      for (int j = 0; j < 4; ++j) {
        float p = __expf(s[j][reg] - mNew);
        s[j][reg] = p;
        rs += p;
      }
      rs += __shfl_xor(rs, 1);
      rs += __shfl_xor(rs, 2);
      rs += __shfl_xor(rs, 4);
      rs += __shfl_xor(rs, 8);
      lSt[reg] = lSt[reg] * alpha + rs;
#pragma unroll
      for (int j = 0; j < 4; ++j) accO[j][reg] *= alpha;
    }
#pragma unroll
    for (int j = 0; j < 4; ++j)
#pragma unroll
      for (int reg = 0; reg < 4; ++reg)
        *(u16*)&Ps[w * 16 + quad * 4 + reg][j * 16 + l16] = f2b(s[j][reg]);
    __syncthreads();
    bf16x8 aP0 = *(const bf16x8*)&Ps[w * 16 + l16][quad * 8];
    bf16x8 aP1 = *(const bf16x8*)&Ps[w * 16 + l16][32 + quad * 8];
#pragma unroll
    for (int jd = 0; jd < 4; ++jd) {
      bf16x8 b0 = *(const bf16x8*)&Vs[jd * 16 + l16][quad * 8];
      bf16x8 b1 = *(const bf16x8*)&Vs[jd * 16 + l16][32 + quad * 8];
      accO[jd] = MFMA16(aP0, b0, accO[jd]);
      accO[jd] = MFMA16(aP1, b1, accO[jd]);
    }
    __syncthreads();
  }
#pragma unroll
  for (int reg = 0; reg < 4; ++reg) {
    float inv = 1.0f / lSt[reg];
    int row = q0 + w * 16 + quad * 4 + reg;
#pragma unroll
    for (int jd = 0; jd < 4; ++jd)
      o[((size_t)(b * SEQ + row)) * DIM + h * DHEAD + jd * 16 + l16] =
          f2b(accO[jd][reg] * inv);
  }
}

// ---------------- split-K reduce + bias + residual + LayerNorm (one row/block)
__global__ __launch_bounds__(256) void k_red_ln(const float* __restrict__ part, int KS,
                                                const float* __restrict__ bias,
                                                float* __restrict__ f,
                                                u16* __restrict__ fb,
                                                const float* __restrict__ s,
                                                const float* __restrict__ bvec) {
  const int row = blockIdx.x;
  const int t = threadIdx.x;
  const size_t base = (size_t)row * DIM;
  float x0 = f[base + t] + bias[t];
  float x1 = f[base + t + 256] + bias[t + 256];
  for (int z = 0; z < KS; ++z) {
    x0 += part[(size_t)z * NTOK * DIM + base + t];
    x1 += part[(size_t)z * NTOK * DIM + base + t + 256];
  }
  float sum = x0 + x1;
  float sq = x0 * x0 + x1 * x1;
#pragma unroll
  for (int off = 32; off; off >>= 1) {
    sum += __shfl_xor(sum, off);
    sq += __shfl_xor(sq, off);
  }
  __shared__ float rs[4], rq[4];
  const int w = t >> 6, lane = t & 63;
  if (lane == 0) { rs[w] = sum; rq[w] = sq; }
  __syncthreads();
  float tot = rs[0] + rs[1] + rs[2] + rs[3];
  float tq2 = rq[0] + rq[1] + rq[2] + rq[3];
  float mu = tot * (1.0f / 512.0f);
  float var = tq2 * (1.0f / 512.0f) - mu * mu;
  float rstd = rsqrtf(var + 1e-5f);
  float v0 = (x0 - mu) * rstd * s[t] + bvec[t];
  float v1 = (x1 - mu) * rstd * s[t + 256] + bvec[t + 256];
  f[base + t] = v0;
  f[base + t + 256] = v1;
  fb[base + t] = f2b(v0);
  fb[base + t + 256] = f2b(v1);
}

// ---------------- gather init-slot rows into compact A for post GEMM
__global__ __launch_bounds__(256) void k_gather(const u16* __restrict__ fb,
                                                u16* __restrict__ Ap) {
  int i = blockIdx.x * 256 + threadIdx.x;   // < MPOST*512
  int m = i >> 9, d = i & 511;
  int p = m & 63, pr = (m >> 6) % PAIRS, b = m / (PAIRS * PP);
  int g = b * SEQ + pr * 128 + p;
  Ap[i] = fb[(size_t)g * DIM + d];
}

// ---------------- post bias + depatchify scatter
__global__ __launch_bounds__(256) void k_scatter(const float* __restrict__ part,
                                                 const float* __restrict__ bias,
                                                 float* __restrict__ out) {
  int i = blockIdx.x * 256 + threadIdx.x;   // < MPOST*512
  int m = i >> 9, n = i & 511;
  float v = part[i] + bias[n];
  int p = m & 63, pr = (m >> 6) % PAIRS, b = m / (PAIRS * PP);
  int c = n >> 8, r1 = (n >> 4) & 15, r2 = n & 15;
  int row = ((p >> 3) << 4) + r1, col = ((p & 7) << 4) + r2;
  size_t off = ((size_t)((b * PAIRS + pr) * NCH + c) << 14) + (size_t)row * HWP + col;
  out[off] = v;
}

extern "C" void kernel_launch(void* const* d_in, const int* in_sizes, int n_in,
                              void* d_out, int out_size, void* d_ws, size_t ws_size,
                              hipStream_t stream) {
  const float* init = (const float*)d_in[0];
  const float* endp = (const float*)d_in[1];
  const float* pre_W = (const float*)d_in[3];
  const float* pre_b = (const float*)d_in[4];
  const float* post_W = (const float*)d_in[5];
  const float* post_b = (const float*)d_in[6];
  const float* patch_pos = (const float*)d_in[7];
  const float* func_pos = (const float*)d_in[8];
  const float* Wqkv = (const float*)d_in[9];
  const float* bqkv = (const float*)d_in[10];
  const float* Wo = (const float*)d_in[11];
  const float* bo = (const float*)d_in[12];
  const float* ln1_s = (const float*)d_in[13];
  const float* ln1_b = (const float*)d_in[14];
  const float* ln2_s = (const float*)d_in[15];
  const float* ln2_b = (const float*)d_in[16];
  const float* W1 = (const float*)d_in[17];
  const float* b1 = (const float*)d_in[18];
  const float* W2 = (const float*)d_in[19];
  const float* b2 = (const float*)d_in[20];
  float* out = (float*)d_out;

  // ws layout, ~70.2 MB total
  char* p = (char*)d_ws;
  float* buf_f = (float*)p;    p += (size_t)NTOK * DIM * 4;    // 10.5 MB f32 master
  u16* buf_fb = (u16*)p;       p += (size_t)NTOK * DIM * 2;    // 5.2 MB bf16 stream
  u16* buf_attn = (u16*)p;     p += (size_t)NTOK * DIM * 2;    // 5.2 MB
  u16* shared_b = (u16*)p;     p += (size_t)NTOK * DFF * 2;    // 21 MB (patch/qkv/hid/Apost)
  u16* wB = (u16*)p;           p += (size_t)W_ALL * 2;         // 6.3 MB rotating weights
  u16* wPre = (u16*)p;         p += (size_t)DIM * DIM * 2;
  u16* wPost = (u16*)p;        p += (size_t)DIM * DIM * 2;
  float* partial = (float*)p;  // 2 * NTOK * DIM * 4 = 21 MB (split-K <= 2)
  u16* buf_patch = shared_b;
  u16* buf_qkv = shared_b;
  u16* buf_hid = shared_b;
  u16* buf_apost = shared_b;

  dim3 blk(256);
  const int elems = NTOK * DIM;

  k_cvt2<<<(DIM * DIM + 255) / 256, blk, 0, stream>>>(pre_W, post_W, wPre, wPost,
                                                      DIM * DIM);
  k_patchify<<<elems / 256, blk, 0, stream>>>(init, endp, buf_patch);
  k_mm<<<dim3(DIM / 128, NTOK / 128, 1), blk, 0, stream>>>(
      buf_patch, wPre, nullptr, nullptr, partial, NTOK, DIM, DIM, DIM, 0);
  k_addpos<<<elems / 256, blk, 0, stream>>>(partial, buf_f, buf_fb, pre_b,
                                            patch_pos, func_pos);

  for (int l = 0; l < NLAYER; ++l) {
    k_cvtw<<<W_ALL / 256, blk, 0, stream>>>(
        Wqkv + (size_t)l * W_QKV, Wo + (size_t)l * W_O, W1 + (size_t)l * W_1,
        W2 + (size_t)l * W_1, wB);
    k_mm<<<dim3(3 * DIM / 128, NTOK / 128, 1), blk, 0, stream>>>(
        buf_fb, wB, bqkv + (size_t)l * 3 * DIM, buf_qkv, nullptr,
        NTOK, 3 * DIM, DIM, DIM, 0);
    k_attn<<<dim3(SEQ / 64, NHEAD, BSZ), blk, 0, stream>>>(buf_qkv, buf_attn);
    k_mm<<<dim3(DIM / 128, NTOK / 128, 1), blk, 0, stream>>>(
        buf_attn, wB + OFF_O, nullptr, nullptr, partial, NTOK, DIM, DIM, DIM, 0);
    k_red_ln<<<NTOK, blk, 0, stream>>>(partial, 1, bo + (size_t)l * DIM, buf_f,
                                       buf_fb, ln1_s + (size_t)l * DIM,
                                       ln1_b + (size_t)l * DIM);
    k_mm<<<dim3(DFF / 128, NTOK / 128, 1), blk, 0, stream>>>(
        buf_fb, wB + OFF_1, b1 + (size_t)l * DFF, buf_hid, nullptr,
        NTOK, DFF, DIM, DIM, 1);
    k_mm<<<dim3(DIM / 128, NTOK / 128, 2), blk, 0, stream>>>(
        buf_hid, wB + OFF_2, nullptr, nullptr, partial, NTOK, DIM, DFF, DFF / 2, 0);
    k_red_ln<<<NTOK, blk, 0, stream>>>(partial, 2, b2 + (size_t)l * DIM, buf_f,
                                       buf_fb, ln2_s + (size_t)l * DIM,
                                       ln2_b + (size_t)l * DIM);
  }

  k_gather<<<(MPOST * DIM) / 256, blk, 0, stream>>>(buf_fb, buf_apost);
  k_mm<<<dim3(DIM / 128, MPOST / 128, 1), blk, 0, stream>>>(
      buf_apost, wPost, nullptr, nullptr, partial, MPOST, DIM, DIM, DIM, 0);
  k_scatter<<<(MPOST * DIM) / 256, blk, 0, stream>>>(partial, post_b, out);
}

// Round 5
// 981.494 us; speedup vs baseline: 5.9150x; 1.1845x over previous
//
#include <hip/hip_runtime.h>
#include <hip/hip_bf16.h>

#define BSZ 8
#define PAIRS 5
#define NCH 2
#define HWP 128
#define PP 64
#define DIM 512
#define NHEAD 8
#define DHEAD 64
#define DFF 2048
#define NLAYER 6
#define SEQ 640
#define NTOK (BSZ * SEQ)   // 5120
#define FIN 10
#define MPOST (BSZ * PAIRS * PP)   // 2560

typedef unsigned short u16;
typedef __bf16 bf16_t;
typedef __attribute__((ext_vector_type(8))) __bf16 bf16x8;
typedef __attribute__((ext_vector_type(4))) float f32x4;
#define MFMA16(a, b, c) __builtin_amdgcn_mfma_f32_16x16x32_bf16(a, b, c, 0, 0, 0)

__device__ __forceinline__ u16 f2b(float x) {   // RNE f32->bf16
  unsigned u = __float_as_uint(x);
  return (u16)((u + 0x7fffu + ((u >> 16) & 1u)) >> 16);
}

// tanh-form GELU (error vs exact erf-GELU <~1e-3; margin is 0.032)
__device__ __forceinline__ float gelu_t(float x) {
  float y = 0.7978845608f * (x + 0.044715f * x * x * x);
  y = fminf(fmaxf(y, -10.f), 10.f);
  float e = __expf(2.f * y);
  return 0.5f * x * (1.f + (e - 1.f) / (e + 1.f));
}

// async global->LDS DMA, 16B/lane; LDS dest = wave-uniform base + lane*16
__device__ __forceinline__ void dma16(const u16* g, void* l) {
  __builtin_amdgcn_global_load_lds(
      (const __attribute__((address_space(1))) void*)g,
      (__attribute__((address_space(3))) void*)l, 16, 0, 0);
}

// ---------------- pre/post weight convert (one launch)
__global__ __launch_bounds__(256) void k_cvt2(const float* __restrict__ a,
                                              const float* __restrict__ b,
                                              u16* __restrict__ da,
                                              u16* __restrict__ db, int n) {
  int i = blockIdx.x * 256 + threadIdx.x;
  if (i < n) { da[i] = f2b(a[i]); db[i] = f2b(b[i]); }
}

// ---------------- per-layer weight convert: 4 regions in one launch
#define W_QKV (3 * DIM * DIM)   // 786432
#define W_O (DIM * DIM)         // 262144
#define W_1 (DFF * DIM)         // 1048576
#define OFF_O W_QKV
#define OFF_1 (W_QKV + W_O)
#define OFF_2 (W_QKV + W_O + W_1)
#define W_ALL (W_QKV + W_O + 2 * W_1)   // 3145728
__global__ __launch_bounds__(256) void k_cvtw(const float* __restrict__ wq,
                                              const float* __restrict__ wo,
                                              const float* __restrict__ w1,
                                              const float* __restrict__ w2,
                                              u16* __restrict__ dst) {
  int i = blockIdx.x * 256 + threadIdx.x;   // < W_ALL
  const float* src;
  int off;
  if (i < OFF_O) { src = wq; off = i; }
  else if (i < OFF_1) { src = wo; off = i - OFF_O; }
  else if (i < OFF_2) { src = w1; off = i - OFF_1; }
  else { src = w2; off = i - OFF_2; }
  dst[i] = f2b(src[off]);
}

// ---------------- patchify -> bf16 A[NTOK][512]
__global__ __launch_bounds__(256) void k_patchify(const float* __restrict__ init,
                                                  const float* __restrict__ endp,
                                                  u16* __restrict__ A) {
  int i = blockIdx.x * 256 + threadIdx.x;
  int d = i & 511;
  int g = i >> 9;
  int p = g & 63;
  int fi = (g >> 6) % FIN;
  int b = g / SEQ;
  int e = fi & 1;
  int pr = fi >> 1;
  int c = d >> 8;
  int r1 = (d >> 4) & 15;
  int r2 = d & 15;
  int row = ((p >> 3) << 4) + r1;
  int col = ((p & 7) << 4) + r2;
  const float* src = e ? endp : init;
  size_t off = ((size_t)((b * PAIRS + pr) * NCH + c) << 14) + (size_t)row * HWP + col;
  A[i] = f2b(src[off]);
}

// ---------------- pre-bias + positional adds from raw GEMM partial
__global__ __launch_bounds__(256) void k_addpos(const float* __restrict__ pin,
                                                float* __restrict__ f,
                                                u16* __restrict__ fb,
                                                const float* __restrict__ pre_b,
                                                const float* __restrict__ patch_pos,
                                                const float* __restrict__ func_pos) {
  int i = blockIdx.x * 256 + threadIdx.x;
  int d = i & 511;
  int g = i >> 9;
  int p = g & 63;
  int fi = (g >> 6) % FIN;
  float v = pin[i] + pre_b[d] + patch_pos[p * DIM + d] + func_pos[fi * DIM + d];
  f[i] = v;
  fb[i] = f2b(v);
}

// ---------------- bf16 MFMA GEMM, async global_load_lds double-buffer (m97 style).
// A bf16 [M][K], B bf16 [N][K]. Tile 128(M) x NT(N), BK=32, 4 waves.
// outB: C = act(A·B^T + bias) -> bf16.  else raw f32 partial slice blockIdx.z.
template <int NT>
__global__ __launch_bounds__(256) void k_mma(const u16* __restrict__ A,
                                             const u16* __restrict__ B,
                                             const float* __restrict__ bias,
                                             u16* __restrict__ outB,
                                             float* __restrict__ outP,
                                             int M, int N, int K, int Kblk, int act) {
  constexpr int FJ = NT / 32;
  __shared__ __align__(16) bf16_t As[2][128][32];
  __shared__ __align__(16) bf16_t Bs[2][NT][32];
  const int t = threadIdx.x;
  const int w = t >> 6, lane = t & 63, quad = lane >> 4, l16 = lane & 15;
  int bx = blockIdx.x, by = blockIdx.y;
  if ((gridDim.y & 7) == 0) {       // XCD swizzle: contiguous y-chunk per XCD
    int lin = bx + gridDim.x * by;
    int YT = gridDim.y >> 3;
    int xcd = lin & 7, slot = lin >> 3;
    by = xcd * YT + slot % YT;
    bx = slot / YT;
  }
  const int row0 = by << 7, col0 = bx * NT;
  const size_t kOff = (size_t)blockIdx.z * Kblk;
  const int mB = (w & 1) << 6;
  const int nB = (w >> 1) * (NT / 2);
  const u16* ApL = A + (size_t)(row0 + (lane >> 2)) * K + kOff + ((lane & 3) << 3);
  const u16* BpL = B + (size_t)(col0 + (lane >> 2)) * K + kOff + ((lane & 3) << 3);

  f32x4 acc[4][FJ];
#pragma unroll
  for (int i = 0; i < 4; ++i)
#pragma unroll
    for (int j = 0; j < FJ; ++j) acc[i][j] = (f32x4){0.f, 0.f, 0.f, 0.f};

  auto stage = [&](int bu, int kk) {
    dma16(ApL + (size_t)(w * 32) * K + kk, &As[bu][w * 32][0]);
    dma16(ApL + (size_t)(w * 32 + 16) * K + kk, &As[bu][w * 32 + 16][0]);
    if (NT == 128) {
      dma16(BpL + (size_t)(w * 32) * K + kk, &Bs[bu][w * 32][0]);
      dma16(BpL + (size_t)(w * 32 + 16) * K + kk, &Bs[bu][w * 32 + 16][0]);
    } else {
      dma16(BpL + (size_t)(w * 16) * K + kk, &Bs[bu][w * 16][0]);
    }
  };

  const int iters = Kblk >> 5;
  stage(0, 0);
  for (int it = 0; it < iters; ++it) {
    const int cur = it & 1;
    __syncthreads();   // drains DMA(cur) [vmcnt] + prior ds_reads [lgkm] of buffer cur^1
    if (it + 1 < iters) stage(cur ^ 1, (it + 1) << 5);   // flies under the MFMAs below
    bf16x8 af[4], bfr[FJ];
#pragma unroll
    for (int i = 0; i < 4; ++i)
      af[i] = *(const bf16x8*)&As[cur][mB + i * 16 + l16][quad * 8];
#pragma unroll
    for (int j = 0; j < FJ; ++j)
      bfr[j] = *(const bf16x8*)&Bs[cur][nB + j * 16 + l16][quad * 8];
#pragma unroll
    for (int i = 0; i < 4; ++i)
#pragma unroll
      for (int j = 0; j < FJ; ++j) acc[i][j] = MFMA16(af[i], bfr[j], acc[i][j]);
  }

  if (outB) {
#pragma unroll
    for (int i = 0; i < 4; ++i)
#pragma unroll
      for (int reg = 0; reg < 4; ++reg) {
        int m = row0 + mB + i * 16 + quad * 4 + reg;
#pragma unroll
        for (int j = 0; j < FJ; ++j) {
          int n = col0 + nB + j * 16 + l16;
          float v = acc[i][j][reg] + bias[n];
          if (act) v = gelu_t(v);
          outB[(size_t)m * N + n] = f2b(v);
        }
      }
  } else {
    float* dst = outP + (size_t)blockIdx.z * M * N;
#pragma unroll
    for (int i = 0; i < 4; ++i)
#pragma unroll
      for (int reg = 0; reg < 4; ++reg) {
        int m = row0 + mB + i * 16 + quad * 4 + reg;
#pragma unroll
        for (int j = 0; j < FJ; ++j) {
          int n = col0 + nB + j * 16 + l16;
          dst[(size_t)m * N + n] = acc[i][j][reg];
        }
      }
  }
}

// ---------------- fused flash attention (bf16 MFMA). qkv bf16 [B][S][3*DIM].
__global__ __launch_bounds__(256) void k_attn(const u16* __restrict__ qkv,
                                              u16* __restrict__ o) {
  __shared__ bf16_t Qs[64][72];
  __shared__ bf16_t Ks[64][72];
  __shared__ bf16_t Vs[64][72];   // transposed: Vs[d][tok]
  __shared__ bf16_t Ps[64][72];
  const int t = threadIdx.x;
  const int w = t >> 6, lane = t & 63, quad = lane >> 4, l16 = lane & 15;
  const int qblk = blockIdx.x, h = blockIdx.y, b = blockIdx.z;
  const int q0 = qblk << 6;
  const u16* base = qkv + (size_t)b * SEQ * (3 * DIM);
  const int sr = t >> 2;
  const int sd = (t & 3) << 4;
  {
    const u16* qp = base + (size_t)(q0 + sr) * (3 * DIM) + h * DHEAD + sd;
    *(bf16x8*)&Qs[sr][sd] = *(const bf16x8*)(const void*)qp;
    *(bf16x8*)&Qs[sr][sd + 8] = *(const bf16x8*)(const void*)(qp + 8);
  }
  __syncthreads();
  bf16x8 aQ0 = *(const bf16x8*)&Qs[w * 16 + l16][quad * 8];
  bf16x8 aQ1 = *(const bf16x8*)&Qs[w * 16 + l16][32 + quad * 8];
  f32x4 accO[4];
#pragma unroll
  for (int j = 0; j < 4; ++j) accO[j] = (f32x4){0.f, 0.f, 0.f, 0.f};
  float mSt[4] = {-1e30f, -1e30f, -1e30f, -1e30f};
  float lSt[4] = {0.f, 0.f, 0.f, 0.f};
  const int ntile = qblk + 1;
  for (int kt = 0; kt < ntile; ++kt) {
    {
      const u16* kp = base + (size_t)(kt * 64 + sr) * (3 * DIM) + DIM + h * DHEAD + sd;
      *(bf16x8*)&Ks[sr][sd] = *(const bf16x8*)(const void*)kp;
      *(bf16x8*)&Ks[sr][sd + 8] = *(const bf16x8*)(const void*)(kp + 8);
      const u16* vp = base + (size_t)(kt * 64 + sr) * (3 * DIM) + 2 * DIM + h * DHEAD + sd;
      bf16x8 v0 = *(const bf16x8*)(const void*)vp;
      bf16x8 v1 = *(const bf16x8*)(const void*)(vp + 8);
#pragma unroll
      for (int e = 0; e < 8; ++e) Vs[sd + e][sr] = v0[e];
#pragma unroll
      for (int e = 0; e < 8; ++e) Vs[sd + 8 + e][sr] = v1[e];
    }
    __syncthreads();
    f32x4 s[4];
#pragma unroll
    for (int j = 0; j < 4; ++j) {
      bf16x8 b0 = *(const bf16x8*)&Ks[j * 16 + l16][quad * 8];
      bf16x8 b1 = *(const bf16x8*)&Ks[j * 16 + l16][32 + quad * 8];
      s[j] = (f32x4){0.f, 0.f, 0.f, 0.f};
      s[j] = MFMA16(aQ0, b0, s[j]);
      s[j] = MFMA16(aQ1, b1, s[j]);
      s[j] *= 0.125f;
    }
#pragma unroll
    for (int reg = 0; reg < 4; ++reg) {
      float mx = fmaxf(fmaxf(s[0][reg], s[1][reg]), fmaxf(s[2][reg], s[3][reg]));
      mx = fmaxf(mx, __shfl_xor(mx, 1));
      mx = fmaxf(mx, __shfl_xor(mx, 2));
      mx = fmaxf(mx, __shfl_xor(mx, 4));
      mx = fmaxf(mx, __shfl_xor(mx, 8));
      float mNew = fmaxf(mSt[reg], mx);
      float alpha = __expf(mSt[reg] - mNew);
      mSt[reg] = mNew;
      float rs = 0.f;
#pragma unroll
      for (int j = 0; j < 4; ++j) {
        float p = __expf(s[j][reg] - mNew);
        s[j][reg] = p;
        rs += p;
      }
      rs += __shfl_xor(rs, 1);
      rs += __shfl_xor(rs, 2);
      rs += __shfl_xor(rs, 4);
      rs += __shfl_xor(rs, 8);
      lSt[reg] = lSt[reg] * alpha + rs;
#pragma unroll
      for (int j = 0; j < 4; ++j) accO[j][reg] *= alpha;
    }
#pragma unroll
    for (int j = 0; j < 4; ++j)
#pragma unroll
      for (int reg = 0; reg < 4; ++reg)
        *(u16*)&Ps[w * 16 + quad * 4 + reg][j * 16 + l16] = f2b(s[j][reg]);
    __syncthreads();
    bf16x8 aP0 = *(const bf16x8*)&Ps[w * 16 + l16][quad * 8];
    bf16x8 aP1 = *(const bf16x8*)&Ps[w * 16 + l16][32 + quad * 8];
#pragma unroll
    for (int jd = 0; jd < 4; ++jd) {
      bf16x8 b0 = *(const bf16x8*)&Vs[jd * 16 + l16][quad * 8];
      bf16x8 b1 = *(const bf16x8*)&Vs[jd * 16 + l16][32 + quad * 8];
      accO[jd] = MFMA16(aP0, b0, accO[jd]);
      accO[jd] = MFMA16(aP1, b1, accO[jd]);
    }
    __syncthreads();
  }
#pragma unroll
  for (int reg = 0; reg < 4; ++reg) {
    float inv = 1.0f / lSt[reg];
    int row = q0 + w * 16 + quad * 4 + reg;
#pragma unroll
    for (int jd = 0; jd < 4; ++jd)
      o[((size_t)(b * SEQ + row)) * DIM + h * DHEAD + jd * 16 + l16] =
          f2b(accO[jd][reg] * inv);
  }
}

// ---------------- split-K reduce + bias + residual + LayerNorm (one row/block)
__global__ __launch_bounds__(256) void k_red_ln(const float* __restrict__ part, int KS,
                                                const float* __restrict__ bias,
                                                float* __restrict__ f,
                                                u16* __restrict__ fb,
                                                const float* __restrict__ s,
                                                const float* __restrict__ bvec) {
  const int row = blockIdx.x;
  const int t = threadIdx.x;
  const size_t base = (size_t)row * DIM;
  float x0 = f[base + t] + bias[t];
  float x1 = f[base + t + 256] + bias[t + 256];
  for (int z = 0; z < KS; ++z) {
    x0 += part[(size_t)z * NTOK * DIM + base + t];
    x1 += part[(size_t)z * NTOK * DIM + base + t + 256];
  }
  float sum = x0 + x1;
  float sq = x0 * x0 + x1 * x1;
#pragma unroll
  for (int off = 32; off; off >>= 1) {
    sum += __shfl_xor(sum, off);
    sq += __shfl_xor(sq, off);
  }
  __shared__ float rs[4], rq[4];
  const int w = t >> 6, lane = t & 63;
  if (lane == 0) { rs[w] = sum; rq[w] = sq; }
  __syncthreads();
  float tot = rs[0] + rs[1] + rs[2] + rs[3];
  float tq2 = rq[0] + rq[1] + rq[2] + rq[3];
  float mu = tot * (1.0f / 512.0f);
  float var = tq2 * (1.0f / 512.0f) - mu * mu;
  float rstd = rsqrtf(var + 1e-5f);
  float v0 = (x0 - mu) * rstd * s[t] + bvec[t];
  float v1 = (x1 - mu) * rstd * s[t + 256] + bvec[t + 256];
  f[base + t] = v0;
  f[base + t + 256] = v1;
  fb[base + t] = f2b(v0);
  fb[base + t + 256] = f2b(v1);
}

// ---------------- gather init-slot rows into compact A for post GEMM
__global__ __launch_bounds__(256) void k_gather(const u16* __restrict__ fb,
                                                u16* __restrict__ Ap) {
  int i = blockIdx.x * 256 + threadIdx.x;   // < MPOST*512
  int m = i >> 9, d = i & 511;
  int p = m & 63, pr = (m >> 6) % PAIRS, b = m / (PAIRS * PP);
  int g = b * SEQ + pr * 128 + p;
  Ap[i] = fb[(size_t)g * DIM + d];
}

// ---------------- post bias + depatchify scatter
__global__ __launch_bounds__(256) void k_scatter(const float* __restrict__ part,
                                                 const float* __restrict__ bias,
                                                 float* __restrict__ out) {
  int i = blockIdx.x * 256 + threadIdx.x;   // < MPOST*512
  int m = i >> 9, n = i & 511;
  float v = part[i] + bias[n];
  int p = m & 63, pr = (m >> 6) % PAIRS, b = m / (PAIRS * PP);
  int c = n >> 8, r1 = (n >> 4) & 15, r2 = n & 15;
  int row = ((p >> 3) << 4) + r1, col = ((p & 7) << 4) + r2;
  size_t off = ((size_t)((b * PAIRS + pr) * NCH + c) << 14) + (size_t)row * HWP + col;
  out[off] = v;
}

extern "C" void kernel_launch(void* const* d_in, const int* in_sizes, int n_in,
                              void* d_out, int out_size, void* d_ws, size_t ws_size,
                              hipStream_t stream) {
  const float* init = (const float*)d_in[0];
  const float* endp = (const float*)d_in[1];
  const float* pre_W = (const float*)d_in[3];
  const float* pre_b = (const float*)d_in[4];
  const float* post_W = (const float*)d_in[5];
  const float* post_b = (const float*)d_in[6];
  const float* patch_pos = (const float*)d_in[7];
  const float* func_pos = (const float*)d_in[8];
  const float* Wqkv = (const float*)d_in[9];
  const float* bqkv = (const float*)d_in[10];
  const float* Wo = (const float*)d_in[11];
  const float* bo = (const float*)d_in[12];
  const float* ln1_s = (const float*)d_in[13];
  const float* ln1_b = (const float*)d_in[14];
  const float* ln2_s = (const float*)d_in[15];
  const float* ln2_b = (const float*)d_in[16];
  const float* W1 = (const float*)d_in[17];
  const float* b1 = (const float*)d_in[18];
  const float* W2 = (const float*)d_in[19];
  const float* b2 = (const float*)d_in[20];
  float* out = (float*)d_out;

  // ws layout, ~70.2 MB total (known-good size)
  char* p = (char*)d_ws;
  float* buf_f = (float*)p;    p += (size_t)NTOK * DIM * 4;    // f32 master
  u16* buf_fb = (u16*)p;       p += (size_t)NTOK * DIM * 2;    // bf16 stream
  u16* buf_attn = (u16*)p;     p += (size_t)NTOK * DIM * 2;
  u16* shared_b = (u16*)p;     p += (size_t)NTOK * DFF * 2;    // patch/qkv/hid/Apost alias
  u16* wB = (u16*)p;           p += (size_t)W_ALL * 2;         // rotating layer weights
  u16* wPre = (u16*)p;         p += (size_t)DIM * DIM * 2;
  u16* wPost = (u16*)p;        p += (size_t)DIM * DIM * 2;
  float* partial = (float*)p;  // 2 * NTOK * DIM * 4
  u16* buf_patch = shared_b;
  u16* buf_qkv = shared_b;
  u16* buf_hid = shared_b;
  u16* buf_apost = shared_b;

  dim3 blk(256);
  const int elems = NTOK * DIM;

  k_cvt2<<<(DIM * DIM + 255) / 256, blk, 0, stream>>>(pre_W, post_W, wPre, wPost,
                                                      DIM * DIM);
  k_patchify<<<elems / 256, blk, 0, stream>>>(init, endp, buf_patch);
  k_mma<64><<<dim3(8, 40, 1), blk, 0, stream>>>(
      buf_patch, wPre, nullptr, nullptr, partial, NTOK, DIM, DIM, DIM, 0);
  k_addpos<<<elems / 256, blk, 0, stream>>>(partial, buf_f, buf_fb, pre_b,
                                            patch_pos, func_pos);

  for (int l = 0; l < NLAYER; ++l) {
    k_cvtw<<<W_ALL / 256, blk, 0, stream>>>(
        Wqkv + (size_t)l * W_QKV, Wo + (size_t)l * W_O, W1 + (size_t)l * W_1,
        W2 + (size_t)l * W_1, wB);
    k_mma<128><<<dim3(12, 40, 1), blk, 0, stream>>>(
        buf_fb, wB, bqkv + (size_t)l * 3 * DIM, buf_qkv, nullptr,
        NTOK, 3 * DIM, DIM, DIM, 0);
    k_attn<<<dim3(SEQ / 64, NHEAD, BSZ), blk, 0, stream>>>(buf_qkv, buf_attn);
    k_mma<64><<<dim3(8, 40, 1), blk, 0, stream>>>(
        buf_attn, wB + OFF_O, nullptr, nullptr, partial, NTOK, DIM, DIM, DIM, 0);
    k_red_ln<<<NTOK, blk, 0, stream>>>(partial, 1, bo + (size_t)l * DIM, buf_f,
                                       buf_fb, ln1_s + (size_t)l * DIM,
                                       ln1_b + (size_t)l * DIM);
    k_mma<128><<<dim3(16, 40, 1), blk, 0, stream>>>(
        buf_fb, wB + OFF_1, b1 + (size_t)l * DFF, buf_hid, nullptr,
        NTOK, DFF, DIM, DIM, 1);
    k_mma<64><<<dim3(8, 40, 2), blk, 0, stream>>>(
        buf_hid, wB + OFF_2, nullptr, nullptr, partial, NTOK, DIM, DFF, DFF / 2, 0);
    k_red_ln<<<NTOK, blk, 0, stream>>>(partial, 2, b2 + (size_t)l * DIM, buf_f,
                                       buf_fb, ln2_s + (size_t)l * DIM,
                                       ln2_b + (size_t)l * DIM);
  }

  k_gather<<<(MPOST * DIM) / 256, blk, 0, stream>>>(buf_fb, buf_apost);
  k_mma<64><<<dim3(8, 20, 1), blk, 0, stream>>>(
      buf_apost, wPost, nullptr, nullptr, partial, MPOST, DIM, DIM, DIM, 0);
  k_scatter<<<(MPOST * DIM) / 256, blk, 0, stream>>>(partial, post_b, out);
}